// Round 4
// baseline (151.567 us; speedup 1.0000x reference)
//
#include <hip/hip_runtime.h>
#include <stdint.h>

// LocallyConnected1d: out[b,c,o] = (1/8) * sum_{i<64,k<8} x[b,i,4o+k] * w[c,i,o,k]
// B=128, CIN=64, COUT=64, OUT_DIM=256, K=8, S=4, L=1028. fp32 in/out.
//
// R7: single fused kernel, direct B-gather, no workspace, one barrier.
// Evidence: R5 fused = 48.5us, HBM 14%, occ 16.8% -> latency-bound; traffic
// already near-ideal. R6 two-phase ~47us (wb round-trip + extra launch ate
// the coalescing gain). Fix latency structurally:
//  - B-fragment = w[c, i, 2q..2q+1, 0..7] = ONE aligned 64B line; each lane
//    gathers its own fragment (2x dwordx4), o_lo-paired wave L2-hits the
//    other 32B half. No B-LDS, no transpose, no compute-loop barriers.
//  - A staged once (full K) in 40KB LDS -> 4 blocks/CU = 16 waves/CU (2x R5).
//  - 8 b-eighth blocks sharing q land on one XCD (blk, blk+128 same XCD),
//    so each w line is HBM-fetched once, L2-hit 7x; x windows L2-dedup
//    within the XCD's contiguous q-range.
// Per-wave: 16 kt-steps x {2 ds_read_b64 + 4 global dwordx4 + cvt + 2 MFMA}.

#define CIN_  64
#define COUT_ 64
#define OD_   256
#define K_    8
#define L_    1028

#define ASTR 20   // A_lds row stride in bf16 elems (40 B: non-pow2 -> <=4-way banks)

typedef __attribute__((ext_vector_type(8))) short bf16x8;
typedef __attribute__((ext_vector_type(4))) short short4v;
typedef __attribute__((ext_vector_type(4))) float floatx4;

__device__ __forceinline__ unsigned short f32_to_bf16(float f) {
    union { float f; uint32_t u; } v; v.f = f;
    uint32_t u = v.u;
    u += 0x7FFFu + ((u >> 16) & 1u);   // round-to-nearest-even
    return (unsigned short)(u >> 16);
}

// ---------------- fused: block = (q, b-eighth), grid 1024 ----------------
__global__ __launch_bounds__(256, 4)
void lc1d_fused(const float* __restrict__ x,
                const float* __restrict__ w,
                float* __restrict__ out) {
    __shared__ __align__(16) unsigned short Al[64 * 16 * ASTR];  // 40 KB, full K

    const int tid = threadIdx.x;
    const int blk = blockIdx.x;
    // XCD swizzle: XCD j hosts q in [16j,16j+16); blk,blk+128 -> same XCD
    const int q   = (blk & 7) * 16 + ((blk >> 3) & 15);
    const int bq  = blk >> 7;           // 0..7
    const int b0  = bq * 16;

    const int wave = tid >> 6;
    const int lane = tid & 63;
    const int quad = lane >> 4;
    const int l16  = lane & 15;
    const int o_lo = wave & 1;          // which o of the pair
    const int nth  = wave >> 1;         // c-half (c = nth*32 + n*16 + l16)

    // ---- A staging: rows (iL 0..63, bL 0..15) x 12 floats [8q, 8q+12) ----
    #pragma unroll
    for (int it = 0; it < 16; ++it) {
        const int u   = it * 256 + tid;
        const int t   = u & 3;          // float4 within row; t==3 masked
        const int row = u >> 2;         // 0..1023
        const int bL  = row & 15;
        const int iL  = row >> 4;       // 0..63
        if (t < 3) {
            const float4 v = *(const float4*)(x +
                (size_t)((b0 + bL) * CIN_ + iL) * L_ + q * 8 + t * 4);
            ushort4 sv = make_ushort4(f32_to_bf16(v.x), f32_to_bf16(v.y),
                                      f32_to_bf16(v.z), f32_to_bf16(v.w));
            *(ushort4*)&Al[(iL * 16 + bL) * ASTR + t * 4] = sv;
        }
    }
    __syncthreads();   // the kernel's only barrier

    floatx4 acc[2];
    acc[0] = (floatx4){0.f, 0.f, 0.f, 0.f};
    acc[1] = (floatx4){0.f, 0.f, 0.f, 0.f};

    const int o_g = q * 2 + o_lo;

    // ---- compute: 16 K-steps of 32 (i = kt*4+quad, k = quad*8+j -> j=0..7) ----
    #pragma unroll 4
    for (int kt = 0; kt < 16; ++kt) {
        const int i = kt * 4 + quad;
        const int abase = (i * 16 + l16) * ASTR + o_lo * 4;
        const short4v a_lo = *(const short4v*)&Al[abase];
        const short4v a_hi = *(const short4v*)&Al[abase + 4];
        bf16x8 af;
        af[0] = a_lo[0]; af[1] = a_lo[1]; af[2] = a_lo[2]; af[3] = a_lo[3];
        af[4] = a_hi[0]; af[5] = a_hi[1]; af[6] = a_hi[2]; af[7] = a_hi[3];
        #pragma unroll
        for (int n = 0; n < 2; ++n) {
            const int c = nth * 32 + n * 16 + l16;
            // lane's B fragment: w[c, i, o_g, 0..7] = 32B of an aligned 64B line
            const float4* p = (const float4*)(w +
                ((size_t)((c * CIN_ + i) * OD_ + o_g) << 3));
            const float4 v0 = p[0];
            const float4 v1 = p[1];
            bf16x8 bf;
            bf[0] = f32_to_bf16(v0.x); bf[1] = f32_to_bf16(v0.y);
            bf[2] = f32_to_bf16(v0.z); bf[3] = f32_to_bf16(v0.w);
            bf[4] = f32_to_bf16(v1.x); bf[5] = f32_to_bf16(v1.y);
            bf[6] = f32_to_bf16(v1.z); bf[7] = f32_to_bf16(v1.w);
            acc[n] = __builtin_amdgcn_mfma_f32_16x16x32_bf16(af, bf, acc[n], 0, 0, 0);
        }
    }

    // ---- epilogue: D col=l16 (c), row=quad*4+reg (b); scale 1/sqrt(64) ----
    #pragma unroll
    for (int n = 0; n < 2; ++n) {
        const int c = nth * 32 + n * 16 + l16;
        #pragma unroll
        for (int r = 0; r < 4; ++r) {
            const int b = b0 + quad * 4 + r;
            out[((size_t)b * COUT_ + c) * OD_ + o_g] = acc[n][r] * 0.125f;
        }
    }
}

extern "C" void kernel_launch(void* const* d_in, const int* in_sizes, int n_in,
                              void* d_out, int out_size, void* d_ws, size_t ws_size,
                              hipStream_t stream) {
    const float* x = (const float*)d_in[0];   // (128, 64, 1028)
    const float* w = (const float*)d_in[1];   // (1, 64, 64, 256, 8)
    float* out = (float*)d_out;               // (128, 64, 256)
    (void)d_ws; (void)ws_size;                // no workspace (R7: fused, direct gather)

    hipLaunchKernelGGL(lc1d_fused, dim3(1024), dim3(256), 0, stream, x, w, out);
}

// Round 5
// 126.694 us; speedup vs baseline: 1.1963x; 1.1963x over previous
//
#include <hip/hip_runtime.h>
#include <stdint.h>

// LocallyConnected1d: out[b,c,o] = (1/8) * sum_{i<64,k<8} x[b,i,4o+k] * w[c,i,o,k]
// B=128, CIN=64, COUT=64, OUT_DIM=256, K=8, S=4, L=1028. fp32 in/out.
//
// R8: R4's coalesced-transpose K1 + R6's flat single-barrier K2.
// Post-mortem R7: per-lane B gather from w = 64 distinct lines per load
// (c-stride 2MB) -> 78us. R6's K1 had the same scatter (hidden ~35us); its
// flat K2 was the fast part. R4's K1 (LDS transpose, coalesced both sides)
// was the fast K1, but its K2 kept chunked barriers (latency-bound, R5-like).
// This round combines the two fast halves:
//  K1 (R4 verbatim minus bank-XOR): w fp32 -> wb bf16, layout
//      [q 128][ch 4][o_lo 2][c 64][i_loc 16][k 8]. Reads 512B/row coalesced,
//      writes 1KB/wave contiguous.
//  K2: grid 1024 (q 128 x bq 8), b-tile 16, A staged once full-K in 40KB LDS
//      (ASTR=20), ONE barrier, then 16 unrolled K-steps reading B fragments
//      DIRECT from wb: wave load = 64 x 16B granules covering 16 full 64B
//      lines (l16*256B + (kt&3)*64B + quad*16B) -> fully line-coalesced.
//      No B-LDS, no compute barriers, 4 blocks/CU = 16 waves/CU.
//      XCD swizzle: q-range [16j,16j+16) on XCD j; 8 bq-blocks share the
//      128KB wb slab in that XCD's L2 (2MB resident < 4MB).

#define CIN_  64
#define COUT_ 64
#define OD_   256
#define K_    8
#define L_    1028

// wb layout: [q 128][ch 4][o_lo 2][c 64][i_loc 16][k 8] bf16 (no XOR: B is
// register-loaded from global, LDS banks irrelevant)
#define WB_PER_Q  65536
#define WB_PER_CH 16384

#define ASTR 20   // A_lds row stride in bf16 elems (40 B, non-pow2)

typedef __attribute__((ext_vector_type(8))) short bf16x8;
typedef __attribute__((ext_vector_type(4))) short short4v;
typedef __attribute__((ext_vector_type(4))) float floatx4;

__device__ __forceinline__ unsigned short f32_to_bf16(float f) {
    union { float f; uint32_t u; } v; v.f = f;
    uint32_t u = v.u;
    u += 0x7FFFu + ((u >> 16) & 1u);   // round-to-nearest-even
    return (unsigned short)(u >> 16);
}

// ---------------- K1: w fp32 -> wb bf16 (transpose, coalesced) ----------------
// grid 512 = 8 c-tiles(8) x 4 i-tiles(16) x 16 o-tiles(16). 256 threads.
__global__ __launch_bounds__(256, 2)
void lc1d_wprep(const float* __restrict__ w, unsigned short* __restrict__ wb) {
    __shared__ __align__(16) unsigned short tile[128 * 136];  // (c,i) rows x (16o x 8k), pad 8

    const int tid = threadIdx.x;
    const int bx  = blockIdx.x;
    const int c0  = (bx & 7) * 8;
    const int ch  = (bx >> 3) & 3;
    const int i0  = ch * 16;
    const int ot  = bx >> 5;           // 0..15
    const int o0  = ot * 16;
    const int q0  = ot * 8;

    // read: 128 rows (c,i) x 512 B contiguous (16 o x 8 k floats)
    #pragma unroll
    for (int it = 0; it < 16; ++it) {
        const int u   = it * 256 + tid;
        const int t   = u & 31;         // float4 within row
        const int row = u >> 5;         // cL*16 + iL
        const int iL  = row & 15;
        const int cL  = row >> 4;
        const float4 v = *(const float4*)(w +
            (size_t)((c0 + cL) * CIN_ + (i0 + iL)) * (OD_ * K_) + o0 * K_ + t * 4);
        ushort4 sv = make_ushort4(f32_to_bf16(v.x), f32_to_bf16(v.y),
                                  f32_to_bf16(v.z), f32_to_bf16(v.w));
        *(ushort4*)&tile[row * 136 + t * 4] = sv;
    }
    __syncthreads();

    // write: granule (qL, o_lo, cL, i_loc) -> contiguous 16 B stores in wb order
    #pragma unroll
    for (int it = 0; it < 8; ++it) {
        const int u    = it * 256 + tid;
        const int il   = u & 15;        // i_loc (no XOR)
        const int cL   = (u >> 4) & 7;
        const int o_lo = (u >> 7) & 1;
        const int qL   = u >> 8;        // 0..7
        const int c    = c0 + cL;
        const int row  = cL * 16 + il;
        const int o_loc = qL * 2 + o_lo;
        const bf16x8 vv = *(const bf16x8*)&tile[row * 136 + o_loc * 8];
        const size_t dst = (size_t)(q0 + qL) * WB_PER_Q + (size_t)ch * WB_PER_CH
                         + ((size_t)((o_lo * 64 + c) * 16 + il) << 3);
        *(bf16x8*)&wb[dst] = vv;
    }
}

// ---------------- K2: GEMM. block = (q, b-eighth), grid 1024 ----------------
__global__ __launch_bounds__(256, 4)
void lc1d_gemm(const float* __restrict__ x,
               const unsigned short* __restrict__ wb,
               float* __restrict__ out) {
    __shared__ __align__(16) unsigned short Al[64 * 16 * ASTR];  // 40 KB, full K

    const int tid = threadIdx.x;
    const int blk = blockIdx.x;
    // XCD swizzle: XCD j hosts q in [16j,16j+16); blk,blk+128 -> same XCD
    const int q   = (blk & 7) * 16 + ((blk >> 3) & 15);
    const int bq  = blk >> 7;           // 0..7
    const int b0  = bq * 16;

    const int wave = tid >> 6;
    const int lane = tid & 63;
    const int quad = lane >> 4;
    const int l16  = lane & 15;
    const int o_lo = wave & 1;          // which o of the pair
    const int nth  = wave >> 1;         // c-half (c = nth*32 + n*16 + l16)

    // ---- A staging: rows (iL 0..63, bL 0..15) x 12 floats [8q, 8q+12) ----
    #pragma unroll
    for (int it = 0; it < 16; ++it) {
        const int u   = it * 256 + tid;
        const int t   = u & 3;          // float4 within row; t==3 masked
        const int row = u >> 2;         // 0..1023
        const int bL  = row & 15;
        const int iL  = row >> 4;       // 0..63
        if (t < 3) {
            const float4 v = *(const float4*)(x +
                (size_t)((b0 + bL) * CIN_ + iL) * L_ + q * 8 + t * 4);
            ushort4 sv = make_ushort4(f32_to_bf16(v.x), f32_to_bf16(v.y),
                                      f32_to_bf16(v.z), f32_to_bf16(v.w));
            *(ushort4*)&Al[(iL * 16 + bL) * ASTR + t * 4] = sv;
        }
    }
    __syncthreads();   // the kernel's only barrier

    floatx4 acc[2];
    acc[0] = (floatx4){0.f, 0.f, 0.f, 0.f};
    acc[1] = (floatx4){0.f, 0.f, 0.f, 0.f};

    const int o_g = q * 2 + o_lo;
    // lane-constant part of the wb ushort index (granule*8):
    // q*65536 + [(o_lo*64 + nth*32 + n*16 + l16)*16 + i_loc]*8, i_loc=(kt&3)*4+quad
    const size_t wbase = (size_t)q * WB_PER_Q
                       + ((size_t)(o_lo * 64 + nth * 32 + l16) << 7) + (quad << 3);

    // ---- compute: 16 K-steps of 32 (i = kt*4+quad, k = 0..7) ----
    #pragma unroll
    for (int kt = 0; kt < 16; ++kt) {
        const int abase = ((kt * 4 + quad) * 16 + l16) * ASTR + o_lo * 4;
        const short4v a_lo = *(const short4v*)&Al[abase];
        const short4v a_hi = *(const short4v*)&Al[abase + 4];
        bf16x8 af;
        af[0] = a_lo[0]; af[1] = a_lo[1]; af[2] = a_lo[2]; af[3] = a_lo[3];
        af[4] = a_hi[0]; af[5] = a_hi[1]; af[6] = a_hi[2]; af[7] = a_hi[3];
        const size_t kbase = wbase + (kt >> 2) * WB_PER_CH + ((kt & 3) << 5);
        #pragma unroll
        for (int n = 0; n < 2; ++n) {
            // wave load = 64 granules covering 16 full 64B lines (coalesced)
            const bf16x8 bf = *(const bf16x8*)&wb[kbase + (size_t)(n << 11)];
            acc[n] = __builtin_amdgcn_mfma_f32_16x16x32_bf16(af, bf, acc[n], 0, 0, 0);
        }
    }

    // ---- epilogue: D col=l16 (c), row=quad*4+reg (b); scale 1/sqrt(64) ----
    #pragma unroll
    for (int n = 0; n < 2; ++n) {
        const int c = nth * 32 + n * 16 + l16;
        #pragma unroll
        for (int r = 0; r < 4; ++r) {
            const int b = b0 + quad * 4 + r;
            out[((size_t)b * COUT_ + c) * OD_ + o_g] = acc[n][r] * 0.125f;
        }
    }
}

extern "C" void kernel_launch(void* const* d_in, const int* in_sizes, int n_in,
                              void* d_out, int out_size, void* d_ws, size_t ws_size,
                              hipStream_t stream) {
    const float* x = (const float*)d_in[0];   // (128, 64, 1028)
    const float* w = (const float*)d_in[1];   // (1, 64, 64, 256, 8)
    float* out = (float*)d_out;               // (128, 64, 256)
    unsigned short* wb = (unsigned short*)d_ws; // 16 MB bf16 fragment-major

    hipLaunchKernelGGL(lc1d_wprep, dim3(512), dim3(256), 0, stream, w, wb);
    hipLaunchKernelGGL(lc1d_gemm,  dim3(1024), dim3(256), 0, stream, x, wb, out);
}